// Round 6
// baseline (51.695 us; speedup 1.0000x reference)
//
#include <hip/hip_runtime.h>

// Fused elastic wave time step (seistorch), B=4, NZ=NX=1024, f32.
// Barrier-free, LDS-free: one block = one full x-row (256 thr x float4),
// marching an R=4 strip in z. Velocity needs fresh stress at x+4 / x-1 in the
// same row -> fetched from the neighbor lane via __shfl; wave-boundary lanes
// (0 / 63) compute that one halo stress column redundantly from predicated
// scalar loads. z-1 stress terms roll in registers. Circular wrap via &(N-1).
// XCD-aware bijective swizzle: each XCD owns a contiguous strip range so
// adjacent strips' shared halo rows hit the same per-XCD L2.

constexpr int Bn = 4, NZ = 1024, NX = 1024;
constexpr int PLANE = NZ * NX;
constexpr int NPTS = Bn * PLANE;
constexpr int R = 4;                 // rows per strip
constexpr int NSTRIP = NZ / R;       // 256
constexpr int LOG_NSTRIP = 8;
constexpr int NWG = Bn * NSTRIP;     // 1024 blocks

__global__ __launch_bounds__(256) void fused_wave_kernel(
    const float* __restrict__ vp, const float* __restrict__ vs,
    const float* __restrict__ rho, const float* __restrict__ vx,
    const float* __restrict__ vz, const float* __restrict__ txx,
    const float* __restrict__ tzz, const float* __restrict__ txz,
    const float* __restrict__ dtp, const float* __restrict__ hp,
    const float* __restrict__ dpml,
    float* __restrict__ y_vx, float* __restrict__ y_vz,
    float* __restrict__ y_txx, float* __restrict__ y_tzz,
    float* __restrict__ y_txz)
{
    const int tid = threadIdx.x;
    const int lane = tid & 63;
    const int x0 = tid * 4;
    const int xm1 = (x0 - 1) & (NX - 1);
    const int xp4 = (x0 + 4) & (NX - 1);

    // XCD-aware bijective swizzle (NWG % 8 == 0): round-robin dispatch puts
    // bid%8==c on XCD c; give each XCD a contiguous range of work ids.
    const int w = (blockIdx.x & 7) * (NWG / 8) + (blockIdx.x >> 3);
    const int strip = w & (NSTRIP - 1);
    const int b = w >> LOG_NSTRIP;
    const int z0 = strip * R;
    const size_t fb = (size_t)b * PLANE;

    const float dt = dtp[0], h = hp[0];
    const float dth = dt / h;

    // ---- prologue: vx/vz row z0-1 ----
    const int r0 = (z0 - 1) & (NZ - 1);
    const size_t rb0 = fb + (size_t)r0 * NX;
    float4 cvx = *(const float4*)(vx + rb0 + x0);
    float4 cvz = *(const float4*)(vz + rb0 + x0);
    float  cvxm = vx[rb0 + xm1];
    float  cvzp = vz[rb0 + xp4];
    float  cvxp = 0.f, cvzm = 0.f;
    if (lane == 63) cvxp = vx[rb0 + xp4];
    if (lane == 0)  cvzm = vz[rb0 + xm1];

    float p_tzz[4] = {0, 0, 0, 0};
    float p_txz[4] = {0, 0, 0, 0};

#pragma unroll
    for (int k = 0; k <= R; ++k) {
        const int r  = (z0 - 1 + k) & (NZ - 1);
        const int rp = (r + 1) & (NZ - 1);
        const size_t rowb  = fb + (size_t)r * NX;
        const size_t rowbp = fb + (size_t)rp * NX;
        const int mrow = r * NX;

        // row r+1 vx/vz (needed by stress row r), row r materials + old stress
        float4 nvx = *(const float4*)(vx + rowbp + x0);
        float4 nvz = *(const float4*)(vz + rowbp + x0);
        float  nvxm = vx[rowbp + xm1];
        float  nvzp = vz[rowbp + xp4];
        float  nvxp = 0.f, nvzm = 0.f;
        float4 ctxx = *(const float4*)(txx + rowb + x0);
        float4 ctzz = *(const float4*)(tzz + rowb + x0);
        float4 ctxz = *(const float4*)(txz + rowb + x0);
        float4 cvp = *(const float4*)(vp + mrow + x0);
        float4 cvs = *(const float4*)(vs + mrow + x0);
        float4 crh = *(const float4*)(rho + mrow + x0);
        float4 cd  = *(const float4*)(dpml + mrow + x0);

        // halo-lane extras
        float txxh_o = 0.f, vph = 0.f, vsh = 0.f, rhh = 0.f, dh = 0.f;
        float txzh_o = 0.f, vsl = 0.f, rhl = 0.f, dl = 0.f;
        if (lane == 63) {
            nvxp   = vx[rowbp + xp4];
            txxh_o = txx[rowb + xp4];
            vph = vp[mrow + xp4]; vsh = vs[mrow + xp4];
            rhh = rho[mrow + xp4]; dh = dpml[mrow + xp4];
        }
        if (lane == 0) {
            nvzm   = vz[rowbp + xm1];
            txzh_o = txz[rowb + xm1];
            vsl = vs[mrow + xm1]; rhl = rho[mrow + xm1];
            dl = dpml[mrow + xm1];
        }

        // ---- own stress row r ----
        float fvx[5]  = {cvxm, cvx.x, cvx.y, cvx.z, cvx.w};
        float fvz[5]  = {cvz.x, cvz.y, cvz.z, cvz.w, cvzp};
        float fvx1[4] = {nvx.x, nvx.y, nvx.z, nvx.w};
        float fvz1[4] = {nvz.x, nvz.y, nvz.z, nvz.w};
        float ftxxo[4] = {ctxx.x, ctxx.y, ctxx.z, ctxx.w};
        float ftzzo[4] = {ctzz.x, ctzz.y, ctzz.z, ctzz.w};
        float ftxzo[4] = {ctxz.x, ctxz.y, ctxz.z, ctxz.w};
        float fvp[4] = {cvp.x, cvp.y, cvp.z, cvp.w};
        float fvs[4] = {cvs.x, cvs.y, cvs.z, cvs.w};
        float frh[4] = {crh.x, crh.y, crh.z, crh.w};
        float fd[4]  = {cd.x, cd.y, cd.z, cd.w};

        float o_txx[4], o_tzz[4], o_txz[4], inv[4], omc[4];
#pragma unroll
        for (int i = 0; i < 4; ++i) {
            float lam = frh[i] * (fvp[i] * fvp[i] - 2.0f * fvs[i] * fvs[i]);
            float mu  = frh[i] * fvs[i] * fvs[i];
            float vx_x = fvx[i + 1] - fvx[i];     // vx[x] - vx[x-1]
            float vz_z = fvz1[i] - fvz[i];        // vz[z+1] - vz[z]
            float vx_z = fvx1[i] - fvx[i + 1];    // vx[z+1] - vx[z]
            float vz_x = fvz[i + 1] - fvz[i];     // vz[x+1] - vz[x]
            float c = 0.5f * dt * fd[i];
            inv[i] = 1.0f / (1.0f + c);
            omc[i] = 1.0f - c;
            float lp2m = lam + 2.0f * mu;
            o_txx[i] = inv[i] * (dth * (lp2m * vx_x + lam * vz_z) + omc[i] * ftxxo[i]);
            o_tzz[i] = inv[i] * (dth * (lp2m * vz_z + lam * vx_x) + omc[i] * ftzzo[i]);
            o_txz[i] = inv[i] * (dth * mu * (vz_x + vx_z) + omc[i] * ftxzo[i]);
        }

        // ---- redundant halo stresses (used only on lanes 63 / 0) ----
        float txxh, txzh;
        {   // lane 63: txx at column x0+4, row r
            float lamh = rhh * (vph * vph - 2.0f * vsh * vsh);
            float muh  = rhh * vsh * vsh;
            float vxxh = cvxp - cvx.w;       // vx[x+4] - vx[x+3]
            float vzzh = nvzp - cvzp;        // vz[z+1,x+4] - vz[z,x+4]
            float ch = 0.5f * dt * dh;
            txxh = (1.0f / (1.0f + ch)) *
                   (dth * ((lamh + 2.0f * muh) * vxxh + lamh * vzzh) +
                    (1.0f - ch) * txxh_o);
        }
        {   // lane 0: txz at column x0-1, row r
            float mul = rhl * vsl * vsl;
            float vzxl = cvz.x - cvzm;       // vz[x0] - vz[x0-1]
            float vxzl = nvxm - cvxm;        // vx[z+1,x0-1] - vx[z,x0-1]
            float cl = 0.5f * dt * dl;
            txzh = (1.0f / (1.0f + cl)) *
                   (dth * mul * (vzxl + vxzl) + (1.0f - cl) * txzh_o);
        }

        float txxp4 = __shfl_down(o_txx[0], 1);
        float txzm1 = __shfl_up(o_txz[3], 1);
        if (lane == 63) txxp4 = txxh;
        if (lane == 0)  txzm1 = txzh;

        if (k > 0) {
            *(float4*)(y_txx + rowb + x0) = make_float4(o_txx[0], o_txx[1], o_txx[2], o_txx[3]);
            *(float4*)(y_tzz + rowb + x0) = make_float4(o_tzz[0], o_tzz[1], o_tzz[2], o_tzz[3]);
            *(float4*)(y_txz + rowb + x0) = make_float4(o_txz[0], o_txz[1], o_txz[2], o_txz[3]);

            float ftxx5[5] = {o_txx[0], o_txx[1], o_txx[2], o_txx[3], txxp4};
            float ftxz5[5] = {txzm1, o_txz[0], o_txz[1], o_txz[2], o_txz[3]};
            float fvxc[4] = {cvx.x, cvx.y, cvx.z, cvx.w};
            float fvzc[4] = {cvz.x, cvz.y, cvz.z, cvz.w};

            float o_vx[4], o_vz[4];
#pragma unroll
            for (int i = 0; i < 4; ++i) {
                float txx_x = ftxx5[i + 1] - ftxx5[i];   // txx[x+1]-txx[x]
                float txz_z = ftxz5[i + 1] - p_txz[i];   // txz[z]-txz[z-1]
                float tzz_z = o_tzz[i] - p_tzz[i];       // tzz[z]-tzz[z-1]
                float txz_x = ftxz5[i + 1] - ftxz5[i];   // txz[x]-txz[x-1]
                float s = dth / frh[i];
                o_vx[i] = inv[i] * (s * (txx_x + txz_z) + omc[i] * fvxc[i]);
                o_vz[i] = inv[i] * (s * (txz_x + tzz_z) + omc[i] * fvzc[i]);
            }
            *(float4*)(y_vx + rowb + x0) = make_float4(o_vx[0], o_vx[1], o_vx[2], o_vx[3]);
            *(float4*)(y_vz + rowb + x0) = make_float4(o_vz[0], o_vz[1], o_vz[2], o_vz[3]);
        }

        // ---- roll ----
        cvx = nvx; cvz = nvz;
        cvxm = nvxm; cvzp = nvzp;
        cvxp = nvxp; cvzm = nvzm;
#pragma unroll
        for (int i = 0; i < 4; ++i) { p_tzz[i] = o_tzz[i]; p_txz[i] = o_txz[i]; }
    }
}

extern "C" void kernel_launch(void* const* d_in, const int* in_sizes, int n_in,
                              void* d_out, int out_size, void* d_ws, size_t ws_size,
                              hipStream_t stream) {
    const float* vp  = (const float*)d_in[0];
    const float* vs  = (const float*)d_in[1];
    const float* rho = (const float*)d_in[2];
    const float* vx  = (const float*)d_in[3];
    const float* vz  = (const float*)d_in[4];
    const float* txx = (const float*)d_in[5];
    const float* tzz = (const float*)d_in[6];
    const float* txz = (const float*)d_in[7];
    const float* dtp = (const float*)d_in[8];
    const float* hp  = (const float*)d_in[9];
    const float* dpm = (const float*)d_in[10];

    float* out   = (float*)d_out;
    float* y_vx  = out;
    float* y_vz  = out + (size_t)NPTS;
    float* y_txx = out + 2 * (size_t)NPTS;
    float* y_tzz = out + 3 * (size_t)NPTS;
    float* y_txz = out + 4 * (size_t)NPTS;

    dim3 block(256);
    dim3 grid(NWG);   // 1024 blocks, 4 per CU
    fused_wave_kernel<<<grid, block, 0, stream>>>(vp, vs, rho, vx, vz, txx, tzz, txz,
                                                  dtp, hp, dpm,
                                                  y_vx, y_vz, y_txx, y_tzz, y_txz);
}

// Round 7
// 44.748 us; speedup vs baseline: 1.1552x; 1.1552x over previous
//
#include <hip/hip_runtime.h>

// Fused elastic wave time step (seistorch), B=4, NZ=NX=1024, f32.
// Barrier-free, LDS-free. Each lane handles float2 (2 cols); a 64-lane wave
// covers 128 cols and marches an R=8 row strip in z -> 4096 waves = 4/SIMD
// (2x the float4 version) at unchanged z-halo traffic. Interior x-neighbors
// via __shfl of loaded float2s; wave-boundary lanes (0/63) compute the one
// halo stress column redundantly from predicated scalar loads. z-1 stress
// terms roll in registers. Circular wrap via &(N-1). XCD-bijective swizzle.

constexpr int Bn = 4, NZ = 1024, NX = 1024;
constexpr int PLANE = NZ * NX;
constexpr int NPTS = Bn * PLANE;
constexpr int R = 8;                  // rows per strip
constexpr int NSTRIP = NZ / R;        // 128
constexpr int XSEG = 512;             // cols per 256-thread block
constexpr int NXSEG = NX / XSEG;      // 2
constexpr int NWG = Bn * NSTRIP * NXSEG;  // 1024 blocks

__global__ __launch_bounds__(256) void fused_wave_kernel(
    const float* __restrict__ vp, const float* __restrict__ vs,
    const float* __restrict__ rho, const float* __restrict__ vx,
    const float* __restrict__ vz, const float* __restrict__ txx,
    const float* __restrict__ tzz, const float* __restrict__ txz,
    const float* __restrict__ dtp, const float* __restrict__ hp,
    const float* __restrict__ dpml,
    float* __restrict__ y_vx, float* __restrict__ y_vz,
    float* __restrict__ y_txx, float* __restrict__ y_tzz,
    float* __restrict__ y_txz)
{
    const int tid = threadIdx.x;
    const int lane = tid & 63;

    // XCD-bijective swizzle (NWG % 8 == 0): each XCD gets a contiguous range
    // of work ids -> z-adjacent strips share halo rows in the same L2.
    const int w = (blockIdx.x & 7) * (NWG / 8) + (blockIdx.x >> 3);
    const int xseg  = w & (NXSEG - 1);
    const int strip = (w >> 1) & (NSTRIP - 1);
    const int b     = w >> 8;            // log2(NXSEG*NSTRIP) = 8
    const int z0 = strip * R;
    const int x0 = xseg * XSEG + tid * 2;
    const int xm1 = (x0 - 1) & (NX - 1);
    const int xp2 = (x0 + 2) & (NX - 1);
    const size_t fb = (size_t)b * PLANE;

    const float dt = dtp[0], h = hp[0];
    const float dth = dt / h;

    // ---- prologue: row z0-1 ----
    const int r0 = (z0 - 1) & (NZ - 1);
    const size_t rb0 = fb + (size_t)r0 * NX;
    float2 cvx = *(const float2*)(vx + rb0 + x0);
    float2 cvz = *(const float2*)(vz + rb0 + x0);
    float h_cvxm = 0.f, h_cvzm = 0.f;   // lane 0: vx/vz at x0-1, row r
    float h_cvxp = 0.f, h_cvzp = 0.f;   // lane 63: vx/vz at x0+2, row r
    if (lane == 0)  { h_cvxm = vx[rb0 + xm1]; h_cvzm = vz[rb0 + xm1]; }
    if (lane == 63) { h_cvxp = vx[rb0 + xp2]; h_cvzp = vz[rb0 + xp2]; }

    float p_tzz[2] = {0, 0};
    float p_txz[2] = {0, 0};

#pragma unroll
    for (int k = 0; k <= R; ++k) {
        const int r  = (z0 - 1 + k) & (NZ - 1);
        const int rp = (r + 1) & (NZ - 1);
        const size_t rowb  = fb + (size_t)r * NX;
        const size_t rowbp = fb + (size_t)rp * NX;
        const int mrow = r * NX;

        // row r+1 velocities + row r old stress / materials
        float2 nvx = *(const float2*)(vx + rowbp + x0);
        float2 nvz = *(const float2*)(vz + rowbp + x0);
        float2 ctxx = *(const float2*)(txx + rowb + x0);
        float2 ctzz = *(const float2*)(tzz + rowb + x0);
        float2 ctxz = *(const float2*)(txz + rowb + x0);
        float2 cvp = *(const float2*)(vp + mrow + x0);
        float2 cvs = *(const float2*)(vs + mrow + x0);
        float2 crh = *(const float2*)(rho + mrow + x0);
        float2 cd  = *(const float2*)(dpml + mrow + x0);

        // predicated halo loads
        float h_nvxm = 0.f, h_nvzm = 0.f, h_nvxp = 0.f, h_nvzp = 0.f;
        float txxh_o = 0.f, vph = 0.f, vsh = 0.f, rhh = 0.f, dh = 0.f;
        float txzh_o = 0.f, vsl = 0.f, rhl = 0.f, dl = 0.f;
        if (lane == 0) {
            h_nvxm = vx[rowbp + xm1]; h_nvzm = vz[rowbp + xm1];
            txzh_o = txz[rowb + xm1];
            vsl = vs[mrow + xm1]; rhl = rho[mrow + xm1]; dl = dpml[mrow + xm1];
        }
        if (lane == 63) {
            h_nvxp = vx[rowbp + xp2]; h_nvzp = vz[rowbp + xp2];
            txxh_o = txx[rowb + xp2];
            vph = vp[mrow + xp2]; vsh = vs[mrow + xp2];
            rhh = rho[mrow + xp2]; dh = dpml[mrow + xp2];
        }

        // interior x-neighbors of row r via shfl (boundary lanes patched)
        float vxm = __shfl_up(cvx.y, 1);   if (lane == 0)  vxm = h_cvxm;
        float vzp = __shfl_down(cvz.x, 1); if (lane == 63) vzp = h_cvzp;

        // ---- own stress, cols x0 and x0+1, row r ----
        float fvx[3] = {vxm, cvx.x, cvx.y};
        float fvz[3] = {cvz.x, cvz.y, vzp};
        float fnx[2] = {nvx.x, nvx.y};
        float fnz[2] = {nvz.x, nvz.y};
        float ftxxo[2] = {ctxx.x, ctxx.y};
        float ftzzo[2] = {ctzz.x, ctzz.y};
        float ftxzo[2] = {ctxz.x, ctxz.y};
        float fvp[2] = {cvp.x, cvp.y};
        float fvs[2] = {cvs.x, cvs.y};
        float frh[2] = {crh.x, crh.y};
        float fd[2]  = {cd.x, cd.y};

        float o_txx[2], o_tzz[2], o_txz[2], inv[2], omc[2];
#pragma unroll
        for (int i = 0; i < 2; ++i) {
            float lam = frh[i] * (fvp[i] * fvp[i] - 2.0f * fvs[i] * fvs[i]);
            float mu  = frh[i] * fvs[i] * fvs[i];
            float vx_x = fvx[i + 1] - fvx[i];    // vx[x] - vx[x-1]
            float vz_z = fnz[i] - fvz[i];        // vz[z+1] - vz[z]
            float vx_z = fnx[i] - fvx[i + 1];    // vx[z+1] - vx[z]
            float vz_x = fvz[i + 1] - fvz[i];    // vz[x+1] - vz[x]
            float c = 0.5f * dt * fd[i];
            inv[i] = 1.0f / (1.0f + c);
            omc[i] = 1.0f - c;
            float lp2m = lam + 2.0f * mu;
            o_txx[i] = inv[i] * (dth * (lp2m * vx_x + lam * vz_z) + omc[i] * ftxxo[i]);
            o_tzz[i] = inv[i] * (dth * (lp2m * vz_z + lam * vx_x) + omc[i] * ftzzo[i]);
            o_txz[i] = inv[i] * (dth * mu * (vz_x + vx_z) + omc[i] * ftxzo[i]);
        }

        // ---- redundant halo stresses (valid only on lanes 63 / 0) ----
        float txxh, txzh;
        {   // lane 63: txx at col x0+2, row r
            float lamh = rhh * (vph * vph - 2.0f * vsh * vsh);
            float muh  = rhh * vsh * vsh;
            float vxxh = h_cvxp - cvx.y;     // vx[x+2] - vx[x+1]
            float vzzh = h_nvzp - h_cvzp;    // vz[z+1,x+2] - vz[z,x+2]
            float ch = 0.5f * dt * dh;
            txxh = (1.0f / (1.0f + ch)) *
                   (dth * ((lamh + 2.0f * muh) * vxxh + lamh * vzzh) +
                    (1.0f - ch) * txxh_o);
        }
        {   // lane 0: txz at col x0-1, row r
            float mul = rhl * vsl * vsl;
            float vzxl = cvz.x - h_cvzm;     // vz[x0] - vz[x0-1]
            float vxzl = h_nvxm - h_cvxm;    // vx[z+1,x0-1] - vx[z,x0-1]
            float cl = 0.5f * dt * dl;
            txzh = (1.0f / (1.0f + cl)) *
                   (dth * mul * (vzxl + vxzl) + (1.0f - cl) * txzh_o);
        }

        float txxp2 = __shfl_down(o_txx[0], 1);
        float txzm1 = __shfl_up(o_txz[1], 1);
        if (lane == 63) txxp2 = txxh;
        if (lane == 0)  txzm1 = txzh;

        if (k > 0) {
            *(float2*)(y_txx + rowb + x0) = make_float2(o_txx[0], o_txx[1]);
            *(float2*)(y_tzz + rowb + x0) = make_float2(o_tzz[0], o_tzz[1]);
            *(float2*)(y_txz + rowb + x0) = make_float2(o_txz[0], o_txz[1]);

            float ftxx3[3] = {o_txx[0], o_txx[1], txxp2};
            float ftxz3[3] = {txzm1, o_txz[0], o_txz[1]};
            float fvxc[2] = {cvx.x, cvx.y};
            float fvzc[2] = {cvz.x, cvz.y};

            float o_vx[2], o_vz[2];
#pragma unroll
            for (int i = 0; i < 2; ++i) {
                float txx_x = ftxx3[i + 1] - ftxx3[i];   // txx[x+1]-txx[x]
                float txz_z = ftxz3[i + 1] - p_txz[i];   // txz[z]-txz[z-1]
                float tzz_z = o_tzz[i] - p_tzz[i];       // tzz[z]-tzz[z-1]
                float txz_x = ftxz3[i + 1] - ftxz3[i];   // txz[x]-txz[x-1]
                float s = dth / frh[i];
                o_vx[i] = inv[i] * (s * (txx_x + txz_z) + omc[i] * fvxc[i]);
                o_vz[i] = inv[i] * (s * (txz_x + tzz_z) + omc[i] * fvzc[i]);
            }
            *(float2*)(y_vx + rowb + x0) = make_float2(o_vx[0], o_vx[1]);
            *(float2*)(y_vz + rowb + x0) = make_float2(o_vz[0], o_vz[1]);
        }

        // ---- roll ----
        cvx = nvx; cvz = nvz;
        h_cvxm = h_nvxm; h_cvzm = h_nvzm;
        h_cvxp = h_nvxp; h_cvzp = h_nvzp;
        p_tzz[0] = o_tzz[0]; p_tzz[1] = o_tzz[1];
        p_txz[0] = o_txz[0]; p_txz[1] = o_txz[1];
    }
}

extern "C" void kernel_launch(void* const* d_in, const int* in_sizes, int n_in,
                              void* d_out, int out_size, void* d_ws, size_t ws_size,
                              hipStream_t stream) {
    const float* vp  = (const float*)d_in[0];
    const float* vs  = (const float*)d_in[1];
    const float* rho = (const float*)d_in[2];
    const float* vx  = (const float*)d_in[3];
    const float* vz  = (const float*)d_in[4];
    const float* txx = (const float*)d_in[5];
    const float* tzz = (const float*)d_in[6];
    const float* txz = (const float*)d_in[7];
    const float* dtp = (const float*)d_in[8];
    const float* hp  = (const float*)d_in[9];
    const float* dpm = (const float*)d_in[10];

    float* out   = (float*)d_out;
    float* y_vx  = out;
    float* y_vz  = out + (size_t)NPTS;
    float* y_txx = out + 2 * (size_t)NPTS;
    float* y_tzz = out + 3 * (size_t)NPTS;
    float* y_txz = out + 4 * (size_t)NPTS;

    dim3 block(256);
    dim3 grid(NWG);   // 1024 blocks, 4/CU, 4 waves/SIMD
    fused_wave_kernel<<<grid, block, 0, stream>>>(vp, vs, rho, vx, vz, txx, tzz, txz,
                                                  dtp, hp, dpm,
                                                  y_vx, y_vz, y_txx, y_tzz, y_txz);
}

// Round 9
// 43.924 us; speedup vs baseline: 1.1769x; 1.0187x over previous
//
#include <hip/hip_runtime.h>

// Fused elastic wave time step (seistorch), B=4, NZ=NX=1024, f32.
// R2-structure (best: 34.9us) + three un-confounded upgrades:
//  - 3-slot rolling LDS, ONE raw barrier per row (lgkmcnt-only drain; no
//    vmcnt(0) drain -> compiler-hoisted next-row loads stay in flight)
//  - non-temporal stores for all 5 outputs (outputs never re-read in-kernel)
//    via native ext_vector_type (HIP_vector_type rejected by the builtin)
//  - XCD-bijective block swizzle (z-adjacent strips share halo rows in the
//    same per-XCD L2)
// One block = one full x-row (256 thr x float4 = 1024 = NX), R=8 strip in z.
// Velocity row r consumes stress rows r (regs/LDS) and r-1 (LDS). Circular
// wrap via &(N-1).

typedef float f32x4 __attribute__((ext_vector_type(4)));

constexpr int Bn = 4, NZ = 1024, NX = 1024;
constexpr int PLANE = NZ * NX;
constexpr int NPTS = Bn * PLANE;
constexpr int R = 8;                 // rows per strip
constexpr int NSTRIP = NZ / R;       // 128
constexpr int LOG_NSTRIP = 7;
constexpr int NWG = Bn * NSTRIP;     // 512 blocks (512 % 8 == 0)

__device__ __forceinline__ void nt_store4(float* p, float a, float b, float c, float d) {
    f32x4 v = {a, b, c, d};
    __builtin_nontemporal_store(v, (f32x4*)p);
}

__global__ __launch_bounds__(256, 2) void fused_wave_kernel(
    const float* __restrict__ vp, const float* __restrict__ vs,
    const float* __restrict__ rho, const float* __restrict__ vx,
    const float* __restrict__ vz, const float* __restrict__ txx,
    const float* __restrict__ tzz, const float* __restrict__ txz,
    const float* __restrict__ dtp, const float* __restrict__ hp,
    const float* __restrict__ dpml,
    float* __restrict__ y_vx, float* __restrict__ y_vz,
    float* __restrict__ y_txx, float* __restrict__ y_tzz,
    float* __restrict__ y_txz)
{
    __shared__ float s_txx[3][NX];
    __shared__ float s_tzz[3][NX];
    __shared__ float s_txz[3][NX];

    const int tid = threadIdx.x;
    const int x0 = tid * 4;
    const int xm1 = (x0 - 1) & (NX - 1);
    const int xp4 = (x0 + 4) & (NX - 1);

    // XCD-bijective swizzle: round-robin dispatch puts bid%8 on XCD (bid%8);
    // remap so each XCD owns a contiguous range of work ids.
    const int w = (blockIdx.x & 7) * (NWG / 8) + (blockIdx.x >> 3);
    const int strip = w & (NSTRIP - 1);
    const int b = w >> LOG_NSTRIP;
    const int z0 = strip * R;
    const size_t fb = (size_t)b * PLANE;

    const float dt = dtp[0], h = hp[0];
    const float dth = dt / h;

    const int rm0 = (z0 - 1) & (NZ - 1);
    float4 cvx = *(const float4*)(vx + fb + (size_t)rm0 * NX + x0);
    float4 cvz = *(const float4*)(vz + fb + (size_t)rm0 * NX + x0);

#pragma unroll
    for (int k = 0; k <= R; ++k) {
        const int r  = (z0 - 1 + k) & (NZ - 1);
        const int rp = (r + 1) & (NZ - 1);
        const size_t rowb  = fb + (size_t)r * NX;
        const size_t rowbp = fb + (size_t)rp * NX;
        const int mrow = r * NX;

        float4 nvx = *(const float4*)(vx + rowbp + x0);
        float4 nvz = *(const float4*)(vz + rowbp + x0);
        float  vxm = vx[rowb + xm1];
        float  vzp = vz[rowb + xp4];
        float4 txxo = *(const float4*)(txx + rowb + x0);
        float4 tzzo = *(const float4*)(tzz + rowb + x0);
        float4 txzo = *(const float4*)(txz + rowb + x0);
        float4 cvp = *(const float4*)(vp + mrow + x0);
        float4 cvs = *(const float4*)(vs + mrow + x0);
        float4 crh = *(const float4*)(rho + mrow + x0);
        float4 cd  = *(const float4*)(dpml + mrow + x0);

        float fvx[5]  = {vxm, cvx.x, cvx.y, cvx.z, cvx.w};
        float fvz[5]  = {cvz.x, cvz.y, cvz.z, cvz.w, vzp};
        float fvx1[4] = {nvx.x, nvx.y, nvx.z, nvx.w};
        float fvz1[4] = {nvz.x, nvz.y, nvz.z, nvz.w};
        float ftxxo[4] = {txxo.x, txxo.y, txxo.z, txxo.w};
        float ftzzo[4] = {tzzo.x, tzzo.y, tzzo.z, tzzo.w};
        float ftxzo[4] = {txzo.x, txzo.y, txzo.z, txzo.w};
        float fvp[4] = {cvp.x, cvp.y, cvp.z, cvp.w};
        float fvs[4] = {cvs.x, cvs.y, cvs.z, cvs.w};
        float frh[4] = {crh.x, crh.y, crh.z, crh.w};
        float fd[4]  = {cd.x, cd.y, cd.z, cd.w};

        float o_txx[4], o_tzz[4], o_txz[4], inv[4], omc[4];
#pragma unroll
        for (int i = 0; i < 4; ++i) {
            float lam = frh[i] * (fvp[i] * fvp[i] - 2.0f * fvs[i] * fvs[i]);
            float mu  = frh[i] * fvs[i] * fvs[i];
            float vx_x = fvx[i + 1] - fvx[i];     // vx[x] - vx[x-1]
            float vz_z = fvz1[i] - fvz[i];        // vz[z+1] - vz[z]
            float vx_z = fvx1[i] - fvx[i + 1];    // vx[z+1] - vx[z]
            float vz_x = fvz[i + 1] - fvz[i];     // vz[x+1] - vz[x]
            float c = 0.5f * dt * fd[i];
            inv[i] = 1.0f / (1.0f + c);
            omc[i] = 1.0f - c;
            float lp2m = lam + 2.0f * mu;
            o_txx[i] = inv[i] * (dth * (lp2m * vx_x + lam * vz_z) + omc[i] * ftxxo[i]);
            o_tzz[i] = inv[i] * (dth * (lp2m * vz_z + lam * vx_x) + omc[i] * ftzzo[i]);
            o_txz[i] = inv[i] * (dth * mu * (vz_x + vx_z) + omc[i] * ftxzo[i]);
        }

        const int slot  = k % 3;           // compile-time (unrolled)
        const int pslot = (k + 2) % 3;     // (k-1) % 3
        *(float4*)&s_txx[slot][x0] = make_float4(o_txx[0], o_txx[1], o_txx[2], o_txx[3]);
        *(float4*)&s_tzz[slot][x0] = make_float4(o_tzz[0], o_tzz[1], o_tzz[2], o_tzz[3]);
        *(float4*)&s_txz[slot][x0] = make_float4(o_txz[0], o_txz[1], o_txz[2], o_txz[3]);
        if (k > 0) {
            nt_store4(y_txx + rowb + x0, o_txx[0], o_txx[1], o_txx[2], o_txx[3]);
            nt_store4(y_tzz + rowb + x0, o_tzz[0], o_tzz[1], o_tzz[2], o_tzz[3]);
            nt_store4(y_txz + rowb + x0, o_txz[0], o_txz[1], o_txz[2], o_txz[3]);
        }

        // LDS-only drain + raw barrier: global loads/stores stay in flight.
        // Safe at max skew 1 iteration with 3 slots (writes phase k+1 touch
        // slot (k+1)%3; reads phase k touch k%3,(k-1)%3 -> disjoint).
        asm volatile("s_waitcnt lgkmcnt(0)" ::: "memory");
        __builtin_amdgcn_s_barrier();

        if (k > 0) {
            float  txxp4v = s_txx[slot][xp4];
            float  txzm1v = s_txz[slot][xm1];
            float4 txzzm = *(const float4*)&s_txz[pslot][x0];
            float4 tzzzm = *(const float4*)&s_tzz[pslot][x0];

            float ftxx5[5] = {o_txx[0], o_txx[1], o_txx[2], o_txx[3], txxp4v};
            float ftxz5[5] = {txzm1v, o_txz[0], o_txz[1], o_txz[2], o_txz[3]};
            float ftxzzm[4] = {txzzm.x, txzzm.y, txzzm.z, txzzm.w};
            float ftzzzm[4] = {tzzzm.x, tzzzm.y, tzzzm.z, tzzzm.w};
            float fvxc[4] = {cvx.x, cvx.y, cvx.z, cvx.w};
            float fvzc[4] = {cvz.x, cvz.y, cvz.z, cvz.w};

            float o_vx[4], o_vz[4];
#pragma unroll
            for (int i = 0; i < 4; ++i) {
                float txx_x = ftxx5[i + 1] - ftxx5[i];   // txx[x+1]-txx[x]
                float txz_z = ftxz5[i + 1] - ftxzzm[i];  // txz[z]-txz[z-1]
                float tzz_z = o_tzz[i] - ftzzzm[i];      // tzz[z]-tzz[z-1]
                float txz_x = ftxz5[i + 1] - ftxz5[i];   // txz[x]-txz[x-1]
                float s = dth / frh[i];
                o_vx[i] = inv[i] * (s * (txx_x + txz_z) + omc[i] * fvxc[i]);
                o_vz[i] = inv[i] * (s * (txz_x + tzz_z) + omc[i] * fvzc[i]);
            }
            nt_store4(y_vx + rowb + x0, o_vx[0], o_vx[1], o_vx[2], o_vx[3]);
            nt_store4(y_vz + rowb + x0, o_vz[0], o_vz[1], o_vz[2], o_vz[3]);
        }

        cvx = nvx;
        cvz = nvz;
    }
}

extern "C" void kernel_launch(void* const* d_in, const int* in_sizes, int n_in,
                              void* d_out, int out_size, void* d_ws, size_t ws_size,
                              hipStream_t stream) {
    const float* vp  = (const float*)d_in[0];
    const float* vs  = (const float*)d_in[1];
    const float* rho = (const float*)d_in[2];
    const float* vx  = (const float*)d_in[3];
    const float* vz  = (const float*)d_in[4];
    const float* txx = (const float*)d_in[5];
    const float* tzz = (const float*)d_in[6];
    const float* txz = (const float*)d_in[7];
    const float* dtp = (const float*)d_in[8];
    const float* hp  = (const float*)d_in[9];
    const float* dpm = (const float*)d_in[10];

    float* out   = (float*)d_out;
    float* y_vx  = out;
    float* y_vz  = out + (size_t)NPTS;
    float* y_txx = out + 2 * (size_t)NPTS;
    float* y_tzz = out + 3 * (size_t)NPTS;
    float* y_txz = out + 4 * (size_t)NPTS;

    dim3 block(256);
    dim3 grid(NWG);   // 512 blocks, 2 per CU
    fused_wave_kernel<<<grid, block, 0, stream>>>(vp, vs, rho, vx, vz, txx, tzz, txz,
                                                  dtp, hp, dpm,
                                                  y_vx, y_vz, y_txx, y_tzz, y_txz);
}

// Round 10
// 35.685 us; speedup vs baseline: 1.4486x; 1.2309x over previous
//
#include <hip/hip_runtime.h>

// Fused elastic wave time step (seistorch), B=4, NZ=NX=1024, f32.
// Exactly the R2 structure (best measured: 34.9us) with ONE change:
// 3-slot rolling LDS buffer -> single __syncthreads per row (R2 paid 2).
// Slot safety at max skew 1 iter: phase-k+1 writes slot (k+1)%3; phase-k
// reads slots k%3 and (k-1)%3 -> disjoint. Numerics of the 3-slot scheme
// proven in rounds 3/4/9. No asm fences, no swizzle, no nt-stores (all
// measured regressions). One block = one full x-row (256 thr x float4),
// R=8 strip in z. Circular wrap via &(N-1).

constexpr int Bn = 4, NZ = 1024, NX = 1024;
constexpr int PLANE = NZ * NX;
constexpr int NPTS = Bn * PLANE;
constexpr int R = 8;                 // rows per strip
constexpr int NSTRIP = NZ / R;       // 128
constexpr int LOG_NSTRIP = 7;

__global__ __launch_bounds__(256, 2) void fused_wave_kernel(
    const float* __restrict__ vp, const float* __restrict__ vs,
    const float* __restrict__ rho, const float* __restrict__ vx,
    const float* __restrict__ vz, const float* __restrict__ txx,
    const float* __restrict__ tzz, const float* __restrict__ txz,
    const float* __restrict__ dtp, const float* __restrict__ hp,
    const float* __restrict__ dpml,
    float* __restrict__ y_vx, float* __restrict__ y_vz,
    float* __restrict__ y_txx, float* __restrict__ y_tzz,
    float* __restrict__ y_txz)
{
    __shared__ float s_txx[3][NX];
    __shared__ float s_tzz[3][NX];
    __shared__ float s_txz[3][NX];

    const int tid = threadIdx.x;
    const int x0 = tid * 4;
    const int xm1 = (x0 - 1) & (NX - 1);
    const int xp4 = (x0 + 4) & (NX - 1);
    const int strip = blockIdx.x & (NSTRIP - 1);
    const int b = blockIdx.x >> LOG_NSTRIP;
    const int z0 = strip * R;
    const size_t fb = (size_t)b * PLANE;

    const float dt = dtp[0], h = hp[0];
    const float dth = dt / h;

    const int rm0 = (z0 - 1) & (NZ - 1);
    float4 cvx = *(const float4*)(vx + fb + (size_t)rm0 * NX + x0);
    float4 cvz = *(const float4*)(vz + fb + (size_t)rm0 * NX + x0);

#pragma unroll
    for (int k = 0; k <= R; ++k) {
        const int r  = (z0 - 1 + k) & (NZ - 1);
        const int rp = (r + 1) & (NZ - 1);
        const size_t rowb  = fb + (size_t)r * NX;
        const size_t rowbp = fb + (size_t)rp * NX;
        const int mrow = r * NX;

        float4 nvx = *(const float4*)(vx + rowbp + x0);
        float4 nvz = *(const float4*)(vz + rowbp + x0);
        float  vxm = vx[rowb + xm1];
        float  vzp = vz[rowb + xp4];
        float4 txxo = *(const float4*)(txx + rowb + x0);
        float4 tzzo = *(const float4*)(tzz + rowb + x0);
        float4 txzo = *(const float4*)(txz + rowb + x0);
        float4 cvp = *(const float4*)(vp + mrow + x0);
        float4 cvs = *(const float4*)(vs + mrow + x0);
        float4 crh = *(const float4*)(rho + mrow + x0);
        float4 cd  = *(const float4*)(dpml + mrow + x0);

        float fvx[5]  = {vxm, cvx.x, cvx.y, cvx.z, cvx.w};
        float fvz[5]  = {cvz.x, cvz.y, cvz.z, cvz.w, vzp};
        float fvx1[4] = {nvx.x, nvx.y, nvx.z, nvx.w};
        float fvz1[4] = {nvz.x, nvz.y, nvz.z, nvz.w};
        float ftxxo[4] = {txxo.x, txxo.y, txxo.z, txxo.w};
        float ftzzo[4] = {tzzo.x, tzzo.y, tzzo.z, tzzo.w};
        float ftxzo[4] = {txzo.x, txzo.y, txzo.z, txzo.w};
        float fvp[4] = {cvp.x, cvp.y, cvp.z, cvp.w};
        float fvs[4] = {cvs.x, cvs.y, cvs.z, cvs.w};
        float frh[4] = {crh.x, crh.y, crh.z, crh.w};
        float fd[4]  = {cd.x, cd.y, cd.z, cd.w};

        float o_txx[4], o_tzz[4], o_txz[4], inv[4], omc[4];
#pragma unroll
        for (int i = 0; i < 4; ++i) {
            float lam = frh[i] * (fvp[i] * fvp[i] - 2.0f * fvs[i] * fvs[i]);
            float mu  = frh[i] * fvs[i] * fvs[i];
            float vx_x = fvx[i + 1] - fvx[i];     // vx[x] - vx[x-1]
            float vz_z = fvz1[i] - fvz[i];        // vz[z+1] - vz[z]
            float vx_z = fvx1[i] - fvx[i + 1];    // vx[z+1] - vx[z]
            float vz_x = fvz[i + 1] - fvz[i];     // vz[x+1] - vz[x]
            float c = 0.5f * dt * fd[i];
            inv[i] = 1.0f / (1.0f + c);
            omc[i] = 1.0f - c;
            float lp2m = lam + 2.0f * mu;
            o_txx[i] = inv[i] * (dth * (lp2m * vx_x + lam * vz_z) + omc[i] * ftxxo[i]);
            o_tzz[i] = inv[i] * (dth * (lp2m * vz_z + lam * vx_x) + omc[i] * ftzzo[i]);
            o_txz[i] = inv[i] * (dth * mu * (vz_x + vx_z) + omc[i] * ftxzo[i]);
        }

        const int slot  = k % 3;           // compile-time (unrolled)
        const int pslot = (k + 2) % 3;     // (k-1) % 3
        *(float4*)&s_txx[slot][x0] = make_float4(o_txx[0], o_txx[1], o_txx[2], o_txx[3]);
        *(float4*)&s_tzz[slot][x0] = make_float4(o_tzz[0], o_tzz[1], o_tzz[2], o_tzz[3]);
        *(float4*)&s_txz[slot][x0] = make_float4(o_txz[0], o_txz[1], o_txz[2], o_txz[3]);
        if (k > 0) {
            *(float4*)(y_txx + rowb + x0) = make_float4(o_txx[0], o_txx[1], o_txx[2], o_txx[3]);
            *(float4*)(y_tzz + rowb + x0) = make_float4(o_tzz[0], o_tzz[1], o_tzz[2], o_tzz[3]);
            *(float4*)(y_txz + rowb + x0) = make_float4(o_txz[0], o_txz[1], o_txz[2], o_txz[3]);
        }

        __syncthreads();   // single barrier per row (3-slot makes 2nd redundant)

        if (k > 0) {
            float  txxp4v = s_txx[slot][xp4];
            float  txzm1v = s_txz[slot][xm1];
            float4 txzzm = *(const float4*)&s_txz[pslot][x0];
            float4 tzzzm = *(const float4*)&s_tzz[pslot][x0];

            float ftxx5[5] = {o_txx[0], o_txx[1], o_txx[2], o_txx[3], txxp4v};
            float ftxz5[5] = {txzm1v, o_txz[0], o_txz[1], o_txz[2], o_txz[3]};
            float ftxzzm[4] = {txzzm.x, txzzm.y, txzzm.z, txzzm.w};
            float ftzzzm[4] = {tzzzm.x, tzzzm.y, tzzzm.z, tzzzm.w};
            float fvxc[4] = {cvx.x, cvx.y, cvx.z, cvx.w};
            float fvzc[4] = {cvz.x, cvz.y, cvz.z, cvz.w};

            float o_vx[4], o_vz[4];
#pragma unroll
            for (int i = 0; i < 4; ++i) {
                float txx_x = ftxx5[i + 1] - ftxx5[i];   // txx[x+1]-txx[x]
                float txz_z = ftxz5[i + 1] - ftxzzm[i];  // txz[z]-txz[z-1]
                float tzz_z = o_tzz[i] - ftzzzm[i];      // tzz[z]-tzz[z-1]
                float txz_x = ftxz5[i + 1] - ftxz5[i];   // txz[x]-txz[x-1]
                float s = dth / frh[i];
                o_vx[i] = inv[i] * (s * (txx_x + txz_z) + omc[i] * fvxc[i]);
                o_vz[i] = inv[i] * (s * (txz_x + tzz_z) + omc[i] * fvzc[i]);
            }
            *(float4*)(y_vx + rowb + x0) = make_float4(o_vx[0], o_vx[1], o_vx[2], o_vx[3]);
            *(float4*)(y_vz + rowb + x0) = make_float4(o_vz[0], o_vz[1], o_vz[2], o_vz[3]);
        }

        cvx = nvx;
        cvz = nvz;
    }
}

extern "C" void kernel_launch(void* const* d_in, const int* in_sizes, int n_in,
                              void* d_out, int out_size, void* d_ws, size_t ws_size,
                              hipStream_t stream) {
    const float* vp  = (const float*)d_in[0];
    const float* vs  = (const float*)d_in[1];
    const float* rho = (const float*)d_in[2];
    const float* vx  = (const float*)d_in[3];
    const float* vz  = (const float*)d_in[4];
    const float* txx = (const float*)d_in[5];
    const float* tzz = (const float*)d_in[6];
    const float* txz = (const float*)d_in[7];
    const float* dtp = (const float*)d_in[8];
    const float* hp  = (const float*)d_in[9];
    const float* dpm = (const float*)d_in[10];

    float* out   = (float*)d_out;
    float* y_vx  = out;
    float* y_vz  = out + (size_t)NPTS;
    float* y_txx = out + 2 * (size_t)NPTS;
    float* y_tzz = out + 3 * (size_t)NPTS;
    float* y_txz = out + 4 * (size_t)NPTS;

    dim3 block(256);
    dim3 grid(Bn * NSTRIP);   // 512 blocks, 2 per CU
    fused_wave_kernel<<<grid, block, 0, stream>>>(vp, vs, rho, vx, vz, txx, tzz, txz,
                                                  dtp, hp, dpm,
                                                  y_vx, y_vz, y_txx, y_tzz, y_txz);
}